// Round 11
// baseline (305.949 us; speedup 1.0000x reference)
//
#include <hip/hip_runtime.h>
#include <hip/hip_bf16.h>

// Problem constants
#define NTOK 32768
#define CH   256
#define NEXP 16

typedef __attribute__((ext_vector_type(8)))  short short8;   // 8 x bf16 (4 VGPR)
typedef __attribute__((ext_vector_type(16))) float f32x16;   // MFMA 32x32 accumulator

#define MFMA32(a, b, c) __builtin_amdgcn_mfma_f32_32x32x16_bf16((a), (b), (c), 0, 0, 0)
#define BC8(v) __builtin_bit_cast(short8, (v))

// fp32 -> bf16 round-to-nearest-even
static __device__ __forceinline__ unsigned short f2bf(float f) {
  unsigned int u = __builtin_bit_cast(unsigned int, f);
  unsigned int r = (u + 0x7fffu + ((u >> 16) & 1u)) >> 16;
  return (unsigned short)r;
}

// ---------------------------------------------------------------------------
// Workspace layout (bytes):
//   [0,       2228224)  W_packed  17*C*C bf16, MFMA B-fragment order
//   [2228224, 4325376)  combine   N*16 fp32
//   [4325376, 4390912)  frac_part 512*32 fp32
// ---------------------------------------------------------------------------

// Kernel 1 (unchanged from R9, passed): FUSED prep = gate (blocks 0..511) +
// wconvert (blocks 512..783).
__global__ __launch_bounds__(512, 2) void prep_kernel(
    const float* __restrict__ conv_out, const float* __restrict__ domain_emb,
    const float* __restrict__ gate_W, const float* __restrict__ gate_b,
    const float* __restrict__ ln_gamma, const float* __restrict__ ln_beta,
    const float* __restrict__ share_W, const float* __restrict__ expert_W,
    float* __restrict__ combine, float* __restrict__ frac_part,
    uint4* __restrict__ wp) {
  int t = threadIdx.x, b = blockIdx.x;

  if (b >= 512) {   // ---- wconvert branch ----
    int g = (b - 512) * 512 + t;   // 0..139263 (= 17*8192 exactly)
    int e = g >> 13;
    int r = g & 8191;
    int lane = r & 63;
    int kb = (r >> 6) & 15;
    int db = r >> 10;
    int d  = db * 32 + (lane & 31);
    int k0 = kb * 16 + ((lane >> 5) << 3);
    const float* src = (e < 16) ? (expert_W + (size_t)e * 65536) : share_W;
    unsigned int p[4];
#pragma unroll
    for (int j = 0; j < 4; j++) {
      float f0 = src[(size_t)(k0 + 2 * j) * 256 + d];
      float f1 = src[(size_t)(k0 + 2 * j + 1) * 256 + d];
      p[j] = (unsigned int)f2bf(f0) | ((unsigned int)f2bf(f1) << 16);
    }
    wp[g] = make_uint4(p[0], p[1], p[2], p[3]);
    return;
  }

  // ---- gate branch ----
  __shared__ float route[8][256];                // per-wave private rows
  __shared__ __align__(16) float gwT[16 * 260];  // [e][c], pad 260
  __shared__ float fred[2][8][16];
  int w = t >> 6, l = t & 63;

#pragma unroll
  for (int i = 0; i < 8; i++) {
    int idx = i * 512 + t;
    gwT[(idx & 15) * 260 + (idx >> 4)] = gate_W[idx];
  }
  __syncthreads();

  int lc = l * 4;
  float4 g4 = *(const float4*)(ln_gamma + lc);
  float4 be4 = *(const float4*)(ln_beta + lc);
  float4 de4 = *(const float4*)(domain_emb + lc);
  int e = l & 15, q = l >> 4;
  float gb = gate_b[e];

  float4 gwreg[16];
#pragma unroll
  for (int ii = 0; ii < 16; ii++)
    gwreg[ii] = *(const float4*)&gwT[e * 260 + q * 64 + ii * 4];

  float psel = 0.f, pw = 0.f;
  int n0 = b * 64 + w * 8;
  float4 x = *(const float4*)(conv_out + (size_t)n0 * 256 + lc);
  for (int i = 0; i < 8; i++) {
    float4 xn = *(const float4*)(conv_out + (size_t)(n0 + ((i + 1) & 7)) * 256 + lc);

    float s1 = x.x + x.y + x.z + x.w;
#pragma unroll
    for (int off = 1; off < 64; off <<= 1) s1 += __shfl_xor(s1, off);
    float mu = s1 * (1.f / 256.f);
    float dx = x.x - mu, dy = x.y - mu, dz = x.z - mu, dw = x.w - mu;
    float s2 = dx * dx + dy * dy + dz * dz + dw * dw;
#pragma unroll
    for (int off = 1; off < 64; off <<= 1) s2 += __shfl_xor(s2, off);
    float rstd = rsqrtf(s2 * (1.f / 256.f) + 1e-5f);
    float4 r;
    r.x = dx * rstd * g4.x + be4.x + de4.x;
    r.y = dy * rstd * g4.y + be4.y + de4.y;
    r.z = dz * rstd * g4.z + be4.z + de4.z;
    r.w = dw * rstd * g4.w + be4.w + de4.w;
    *(float4*)(&route[w][lc]) = r;
    asm volatile("s_waitcnt lgkmcnt(0)" ::: "memory");
    __builtin_amdgcn_wave_barrier();

    float a0 = 0.f, a1 = 0.f, a2 = 0.f, a3 = 0.f;
#pragma unroll
    for (int ii = 0; ii < 16; ii += 4) {
      float4 r0 = *(const float4*)(&route[w][q * 64 + (ii + 0) * 4]);
      float4 r1 = *(const float4*)(&route[w][q * 64 + (ii + 1) * 4]);
      float4 r2 = *(const float4*)(&route[w][q * 64 + (ii + 2) * 4]);
      float4 r3 = *(const float4*)(&route[w][q * 64 + (ii + 3) * 4]);
      a0 += r0.x * gwreg[ii + 0].x + r0.y * gwreg[ii + 0].y + r0.z * gwreg[ii + 0].z + r0.w * gwreg[ii + 0].w;
      a1 += r1.x * gwreg[ii + 1].x + r1.y * gwreg[ii + 1].y + r1.z * gwreg[ii + 1].z + r1.w * gwreg[ii + 1].w;
      a2 += r2.x * gwreg[ii + 2].x + r2.y * gwreg[ii + 2].y + r2.z * gwreg[ii + 2].z + r2.w * gwreg[ii + 2].w;
      a3 += r3.x * gwreg[ii + 3].x + r3.y * gwreg[ii + 3].y + r3.z * gwreg[ii + 3].z + r3.w * gwreg[ii + 3].w;
    }
    float acc = (a0 + a1) + (a2 + a3);
    acc += __shfl_xor(acc, 16);
    acc += __shfl_xor(acc, 32);
    float logit = acc + gb;

    float m = logit;
#pragma unroll
    for (int off = 1; off < 16; off <<= 1) m = fmaxf(m, __shfl_xor(m, off));
    float p = expf(logit - m);
    float sum = p;
#pragma unroll
    for (int off = 1; off < 16; off <<= 1) sum += __shfl_xor(sum, off);
    float wv = p / sum;

    float et = -wv * logf(wv + 1e-12f);
    float ent = et;
#pragma unroll
    for (int off = 1; off < 16; off <<= 1) ent += __shfl_xor(ent, off);
    float kf = ceilf(1.f + ent * (15.f / 2.7725887f));
    int k = (int)kf;
    k = max(1, min(16, k));

    int base = l & 48;
    int rank = 0;
#pragma unroll
    for (int j = 0; j < 16; j++) {
      float wj = __shfl(wv, base + j);
      rank += (wj > wv) || (wj == wv && j < e);
    }
    int sel = rank < k;
    float cmb = sel ? wv : 0.f;
    int n = n0 + i;
    if (l < 16) combine[(size_t)n * 16 + e] = cmb;
    psel += (float)sel;
    pw += wv;

    x = xn;
  }

  if (l < 16) { fred[0][w][l] = psel; fred[1][w][l] = pw; }
  __syncthreads();
  if (t < 32) {
    int kind = t >> 4, ee = t & 15;
    float v = 0.f;
#pragma unroll
    for (int ww = 0; ww < 8; ww++) v += fred[kind][ww][ee];
    frac_part[b * 32 + t] = v;
  }
}

// ---- kernel 2 helpers (v9) ----
// B prefetch for flat slot s: e = s>>2, q = s&3; 8 coalesced 1KB lines.
static __device__ __forceinline__ void pref_b(
    uint4 (&breg)[8], const uint4* __restrict__ wb, int s) {
  int en = s >> 2, qn = s & 3;
  const uint4* we = wb + (size_t)en * 8192;
#pragma unroll
  for (int f = 0; f < 8; f++) {
    int kbl = f >> 1, d = f & 1;
    breg[f] = we[(size_t)d * 1024 + (qn * 4 + kbl) * 64];
  }
}

// One flat slot: runtime q (tacc zero-init guard at q==0, scale-add at q==3),
// static register indices throughout (rule #20). A from fragment-ordered LDS
// with kb-XOR swizzle (v7-verified layout). 16 MFMA.
static __device__ __forceinline__ void do_slot(
    f32x16 (&facc)[2][2], f32x16 (&tacc)[2][2], const uint4* __restrict__ at,
    const uint4 (&breg)[8], int s, int abase, int r5,
    const float* __restrict__ wtile, int mbp, int rowoff) {
  int q = s & 3;
  if (q == 0) {
#pragma unroll
    for (int mi = 0; mi < 2; mi++)
#pragma unroll
      for (int d = 0; d < 2; d++)
#pragma unroll
        for (int r = 0; r < 16; r++) tacc[mi][d][r] = 0.f;
  }
  __builtin_amdgcn_s_setprio(1);
#pragma unroll
  for (int kbl = 0; kbl < 4; kbl++) {
    int kb = q * 4 + kbl;
    int ax = kb * 256 + abase + (r5 ^ kb);
    short8 a0 = BC8(at[ax]);
    short8 a1 = BC8(at[ax + 64]);
    short8 b0 = BC8(breg[kbl * 2 + 0]);
    short8 b1 = BC8(breg[kbl * 2 + 1]);
    tacc[0][0] = MFMA32(a0, b0, tacc[0][0]);
    tacc[0][1] = MFMA32(a0, b1, tacc[0][1]);
    tacc[1][0] = MFMA32(a1, b0, tacc[1][0]);
    tacc[1][1] = MFMA32(a1, b1, tacc[1][1]);
  }
  __builtin_amdgcn_s_setprio(0);
  if (q == 3) {
    int e = s >> 2;
    if (e < 16) {
#pragma unroll
      for (int mi = 0; mi < 2; mi++)
#pragma unroll
        for (int rg = 0; rg < 4; rg++) {
          float4 w4 = *(const float4*)&wtile[e * 128 + (mbp * 2 + mi) * 32 + 8 * rg + rowoff];
          float wj[4] = {w4.x, w4.y, w4.z, w4.w};
#pragma unroll
          for (int j = 0; j < 4; j++) {
            facc[mi][0][rg * 4 + j] += wj[j] * tacc[mi][0][rg * 4 + j];
            facc[mi][1][rg * 4 + j] += wj[j] * tacc[mi][1][rg * 4 + j];
          }
        }
    } else {  // shared expert, weight 1.0
#pragma unroll
      for (int mi = 0; mi < 2; mi++)
#pragma unroll
        for (int r = 0; r < 16; r++) {
          facc[mi][0][r] += tacc[mi][0][r];
          facc[mi][1][r] += tacc[mi][1][r];
        }
    }
  }
}

// Kernel 2 (v9, resubmission — R10 failure was container-level, not kernel):
// v7 GEMM structure (128-tok tiles, in-kernel A-stage, barrier-free loop,
// 1 block/CU) + DEPTH-2 B prefetch via 3 rotating register buffers. R9
// falsified the occupancy theory (2x waves, dur flat) => per-wave B-latency
// chain is the limiter (~1950 cyc/slot stall vs ~700 covering compute at
// depth-1). Depth-2 gives ~1300+ cyc of cover. Flat 68-slot loop unrolled
// x3 so buffer indices are compile-time. Block 256 = finalize.
__global__ __launch_bounds__(512, 2) void moe_gemm_kernel(
    const float* __restrict__ inputs, const uint4* __restrict__ wpack,
    const float* __restrict__ combine, const float* __restrict__ expert_b,
    const float* __restrict__ share_b, float* __restrict__ out,
    const float* __restrict__ frac_part) {
  extern __shared__ __align__(16) char smem[];
  int t = threadIdx.x, b = blockIdx.x;

  if (b == 256) {   // ---- finalize branch: balance loss -> out[N*C] ----
    float* acc = (float*)smem;   // [16][32]
    int col = t & 31, seg = t >> 5;   // seg 0..15
    float s = 0.f;
    for (int i = seg; i < 512; i += 16) s += frac_part[i * 32 + col];
    acc[seg * 32 + col] = s;
    __syncthreads();
    if (t < 32) {
      float v = 0.f;
#pragma unroll
      for (int sg = 0; sg < 16; sg++) v += acc[sg * 32 + t];
      acc[t] = v;
    }
    __syncthreads();
    if (t == 0) {
      float loss = 0.f;
      for (int e = 0; e < 16; e++) {
        float ft = acc[e] * (1.f / 32768.f);
        float fp = acc[16 + e] * (1.f / 32768.f);
        loss += ft * fp;
      }
      out[8388608] = loss * 16.f;
    }
    return;
  }

  uint4* at    = (uint4*)smem;              // 4096 uint4 = 64 KB fragment order
  float* wtile = (float*)(smem + 65536);    // [e][row] 16*128 fp32 = 8 KB

  int w = t >> 6, l = t & 63;
  int mbp = w >> 2;      // 0..1 -> rows (mbp*2+{0,1})*32
  int dbp = w & 3;       // 0..3 -> cols (dbp*2+{0,1})*32
  int r5 = l & 31, hi = l >> 5;

  // ---- A-stage: inputs fp32 -> bf16 -> fragment-order LDS (v7-verified) ----
#pragma unroll
  for (int i = 0; i < 8; i++) {
    int idx = i * 512 + t;
    int row = idx >> 5;          // 0..127
    int j = idx & 31;
    const float4* src = (const float4*)(inputs + ((size_t)b * 128 + row) * 256 + j * 8);
    float4 f0 = src[0], f1 = src[1];
    unsigned int p0 = (unsigned int)f2bf(f0.x) | ((unsigned int)f2bf(f0.y) << 16);
    unsigned int p1 = (unsigned int)f2bf(f0.z) | ((unsigned int)f2bf(f0.w) << 16);
    unsigned int p2 = (unsigned int)f2bf(f1.x) | ((unsigned int)f2bf(f1.y) << 16);
    unsigned int p3 = (unsigned int)f2bf(f1.z) | ((unsigned int)f2bf(f1.w) << 16);
    int kb = j >> 1, hib = j & 1;
    at[kb * 256 + (row >> 5) * 64 + hib * 32 + ((row & 31) ^ kb)] =
        make_uint4(p0, p1, p2, p3);
  }
  // wtile transposed stage: combine[tok][e] -> wtile[e*128 + tok]
  {
    const float* cg = combine + (size_t)b * 2048;
#pragma unroll
    for (int i = 0; i < 4; i++) {
      int idx = i * 512 + t;
      wtile[(idx & 15) * 128 + (idx >> 4)] = cg[idx];
    }
  }

  // depth-2 prologue: slots 0 and 1 in flight before the barrier
  const uint4* wb = wpack + (size_t)(dbp * 2) * 1024 + l;
  uint4 bA[8], bB[8], bC[8];
  pref_b(bA, wb, 0);
  pref_b(bB, wb, 1);

  __syncthreads();   // LDS staging visible to all waves

  f32x16 facc[2][2];
#pragma unroll
  for (int mi = 0; mi < 2; mi++)
#pragma unroll
    for (int d = 0; d < 2; d++)
#pragma unroll
      for (int r = 0; r < 16; r++) facc[mi][d][r] = 0.f;
  f32x16 tacc[2][2];

  int rowoff = hi * 4;              // C/D layout row offset
  int abase = mbp * 128 + hi * 32;  // A-frag base for this wave-half

  // flat 68-slot loop, unrolled x3 for static buffer rotation:
  // slot s uses buf[s%3]; prefetch s+2 into buf[(s+2)%3] (freed at s-1).
  for (int s0 = 0; s0 < 68; s0 += 3) {
    {
      int s = s0;
      if (s + 2 < 68) pref_b(bC, wb, s + 2);
      do_slot(facc, tacc, at, bA, s, abase, r5, wtile, mbp, rowoff);
    }
    if (s0 + 1 < 68) {
      int s = s0 + 1;
      if (s + 2 < 68) pref_b(bA, wb, s + 2);
      do_slot(facc, tacc, at, bB, s, abase, r5, wtile, mbp, rowoff);
    }
    if (s0 + 2 < 68) {
      int s = s0 + 2;
      if (s + 2 < 68) pref_b(bB, wb, s + 2);
      do_slot(facc, tacc, at, bC, s, abase, r5, wtile, mbp, rowoff);
    }
  }

  // ---- final epilogue: bias terms + store ----
  int col = r5;
  int cg0 = (dbp * 2 + 0) * 32 + col;
  int cg1 = (dbp * 2 + 1) * 32 + col;
  float sb0 = share_b[cg0], sb1 = share_b[cg1];
  float eb0[16], eb1[16];
#pragma unroll
  for (int e2 = 0; e2 < 16; e2++) {
    eb0[e2] = expert_b[e2 * 256 + cg0];
    eb1[e2] = expert_b[e2 * 256 + cg1];
  }
  // facc += sum_e w[row,e] * expert_b[e,col]
#pragma unroll
  for (int e2 = 0; e2 < 16; e2++)
#pragma unroll
    for (int mi = 0; mi < 2; mi++)
#pragma unroll
      for (int rg = 0; rg < 4; rg++) {
        float4 w4 = *(const float4*)&wtile[e2 * 128 + (mbp * 2 + mi) * 32 + 8 * rg + rowoff];
        float wj[4] = {w4.x, w4.y, w4.z, w4.w};
#pragma unroll
        for (int j = 0; j < 4; j++) {
          facc[mi][0][rg * 4 + j] += wj[j] * eb0[e2];
          facc[mi][1][rg * 4 + j] += wj[j] * eb1[e2];
        }
      }
#pragma unroll
  for (int mi = 0; mi < 2; mi++)
#pragma unroll
    for (int r = 0; r < 16; r++) {
      int row = (mbp * 2 + mi) * 32 + (r & 3) + ((r >> 2) << 3) + rowoff;
      size_t n = (size_t)b * 128 + row;
      out[n * 256 + cg0] = facc[mi][0][r] + sb0;
      out[n * 256 + cg1] = facc[mi][1][r] + sb1;
    }
}

extern "C" void kernel_launch(void* const* d_in, const int* in_sizes, int n_in,
                              void* d_out, int out_size, void* d_ws, size_t ws_size,
                              hipStream_t stream) {
  const float* inputs   = (const float*)d_in[0];
  const float* conv_out = (const float*)d_in[1];
  const float* demb     = (const float*)d_in[2];
  const float* share_W  = (const float*)d_in[3];
  const float* share_b  = (const float*)d_in[4];
  const float* gate_W   = (const float*)d_in[5];
  const float* gate_b   = (const float*)d_in[6];
  const float* expert_W = (const float*)d_in[7];
  const float* expert_b = (const float*)d_in[8];
  const float* ln_g     = (const float*)d_in[9];
  const float* ln_b     = (const float*)d_in[10];
  float* out = (float*)d_out;
  char* ws = (char*)d_ws;

  uint4* wpack   = (uint4*)(ws);
  float* combine = (float*)(ws + 2228224);
  float* frac    = (float*)(ws + 4325376);

  // allow 72 KB dynamic LDS (idempotent; not a stream op, safe under capture)
  hipFuncSetAttribute((const void*)moe_gemm_kernel,
                      hipFuncAttributeMaxDynamicSharedMemorySize, 73728);

  prep_kernel<<<dim3(784), dim3(512), 0, stream>>>(
      conv_out, demb, gate_W, gate_b, ln_g, ln_b, share_W, expert_W,
      combine, frac, wpack);
  moe_gemm_kernel<<<dim3(257), dim3(512), 73728, stream>>>(
      inputs, wpack, combine, expert_b, share_b, out, frac);
}

// Round 12
// 245.040 us; speedup vs baseline: 1.2486x; 1.2486x over previous
//
#include <hip/hip_runtime.h>
#include <hip/hip_bf16.h>

// Problem constants
#define NTOK 32768
#define CH   256
#define NEXP 16

typedef __attribute__((ext_vector_type(8)))  short short8;   // 8 x bf16 (4 VGPR)
typedef __attribute__((ext_vector_type(16))) float f32x16;   // MFMA 32x32 accumulator

#define MFMA32(a, b, c) __builtin_amdgcn_mfma_f32_32x32x16_bf16((a), (b), (c), 0, 0, 0)
#define BC8(v) __builtin_bit_cast(short8, (v))

// fp32 -> bf16 round-to-nearest-even
static __device__ __forceinline__ unsigned short f2bf(float f) {
  unsigned int u = __builtin_bit_cast(unsigned int, f);
  unsigned int r = (u + 0x7fffu + ((u >> 16) & 1u)) >> 16;
  return (unsigned short)r;
}

// ---------------------------------------------------------------------------
// Workspace layout (bytes):
//   [0,        2228224)  W_packed  17*C*C bf16, MFMA B-fragment order
//   [2228224, 19005440)  A_packed  N*C bf16, fragment order per 64-tok tile
//   [19005440,21102592)  combine   N*16 fp32
//   [21102592,21168128)  frac_part 512*32 fp32
// ---------------------------------------------------------------------------

// Kernel 1 (R12): FUSED prep = gate (blocks 0..511) + wconvert (512..783)
// + apack (784..1295). apack branch: inputs fp32 -> bf16 fragment-order
// lines (R8-verified LDS mapping, 64-tok variant) so the GEMM can load
// A-frags DIRECTLY global->VGPR coalesced, no in-gemm conversion.
__global__ __launch_bounds__(512, 2) void prep_kernel(
    const float* __restrict__ inputs, const float* __restrict__ conv_out,
    const float* __restrict__ domain_emb, const float* __restrict__ gate_W,
    const float* __restrict__ gate_b, const float* __restrict__ ln_gamma,
    const float* __restrict__ ln_beta, const float* __restrict__ share_W,
    const float* __restrict__ expert_W, float* __restrict__ combine,
    float* __restrict__ frac_part, uint4* __restrict__ wp,
    uint4* __restrict__ apack) {
  __shared__ __align__(16) char shm[33280];   // union: apack 32KB / gate ~25.9KB
  int t = threadIdx.x, b = blockIdx.x;

  if (b >= 784) {   // ---- apack branch: tile = b - 784 (64 tok) ----
    uint4* at = (uint4*)shm;   // 2048 uint4 = 32 KB, fragment order + kb-XOR
    int tile = b - 784;
    // stage: (row, j) -> at[(j>>1)*128 + (row>>5)*64 + (j&1)*32 + ((row&31)^(j>>1))]
#pragma unroll
    for (int i = 0; i < 4; i++) {
      int u = i * 512 + t;
      int row = u >> 5, j = u & 31;
      const float4* src = (const float4*)(inputs + ((size_t)tile * 64 + row) * 256 + j * 8);
      float4 f0 = src[0], f1 = src[1];
      unsigned int p0 = (unsigned int)f2bf(f0.x) | ((unsigned int)f2bf(f0.y) << 16);
      unsigned int p1 = (unsigned int)f2bf(f0.z) | ((unsigned int)f2bf(f0.w) << 16);
      unsigned int p2 = (unsigned int)f2bf(f1.x) | ((unsigned int)f2bf(f1.y) << 16);
      unsigned int p3 = (unsigned int)f2bf(f1.z) | ((unsigned int)f2bf(f1.w) << 16);
      int kb = j >> 1, hib = j & 1;
      at[kb * 128 + (row >> 5) * 64 + hib * 32 + ((row & 31) ^ kb)] =
          make_uint4(p0, p1, p2, p3);
    }
    __syncthreads();
    // linear copy out (undo the kb-XOR): apack line (kb, mb) lane l = value
    // for A[mb*32 + (l&31)][ch (kb*2 + (l>>5))*8 .. +8]
#pragma unroll
    for (int i = 0; i < 4; i++) {
      int u = i * 512 + t;
      int kb = u >> 7, mb = (u >> 6) & 1, hib = (u >> 5) & 1, r5 = u & 31;
      apack[(size_t)tile * 2048 + u] = at[kb * 128 + mb * 64 + hib * 32 + (r5 ^ kb)];
    }
    return;
  }

  if (b >= 512) {   // ---- wconvert branch (R9-verified) ----
    int g = (b - 512) * 512 + t;   // 0..139263 (= 17*8192 exactly)
    int e = g >> 13;
    int r = g & 8191;
    int lane = r & 63;
    int kb = (r >> 6) & 15;
    int db = r >> 10;
    int d  = db * 32 + (lane & 31);
    int k0 = kb * 16 + ((lane >> 5) << 3);
    const float* src = (e < 16) ? (expert_W + (size_t)e * 65536) : share_W;
    unsigned int p[4];
#pragma unroll
    for (int j = 0; j < 4; j++) {
      float f0 = src[(size_t)(k0 + 2 * j) * 256 + d];
      float f1 = src[(size_t)(k0 + 2 * j + 1) * 256 + d];
      p[j] = (unsigned int)f2bf(f0) | ((unsigned int)f2bf(f1) << 16);
    }
    wp[g] = make_uint4(p[0], p[1], p[2], p[3]);
    return;
  }

  // ---- gate branch (R9-verified math; LDS carved from shm) ----
  float (*route)[256] = (float(*)[256])shm;            // 8 KB
  float* gwT = (float*)(shm + 8192);                   // 16 * 260 fp32 = 16.25 KB
  float* fred = (float*)(shm + 8192 + 16640);          // 2*8*16 fp32 = 1 KB
  int w = t >> 6, l = t & 63;

#pragma unroll
  for (int i = 0; i < 8; i++) {
    int idx = i * 512 + t;
    gwT[(idx & 15) * 260 + (idx >> 4)] = gate_W[idx];
  }
  __syncthreads();

  int lc = l * 4;
  float4 g4 = *(const float4*)(ln_gamma + lc);
  float4 be4 = *(const float4*)(ln_beta + lc);
  float4 de4 = *(const float4*)(domain_emb + lc);
  int e = l & 15, q = l >> 4;
  float gb = gate_b[e];

  float4 gwreg[16];
#pragma unroll
  for (int ii = 0; ii < 16; ii++)
    gwreg[ii] = *(const float4*)&gwT[e * 260 + q * 64 + ii * 4];

  float psel = 0.f, pw = 0.f;
  int n0 = b * 64 + w * 8;
  float4 x = *(const float4*)(conv_out + (size_t)n0 * 256 + lc);
  for (int i = 0; i < 8; i++) {
    float4 xn = *(const float4*)(conv_out + (size_t)(n0 + ((i + 1) & 7)) * 256 + lc);

    float s1 = x.x + x.y + x.z + x.w;
#pragma unroll
    for (int off = 1; off < 64; off <<= 1) s1 += __shfl_xor(s1, off);
    float mu = s1 * (1.f / 256.f);
    float dx = x.x - mu, dy = x.y - mu, dz = x.z - mu, dw = x.w - mu;
    float s2 = dx * dx + dy * dy + dz * dz + dw * dw;
#pragma unroll
    for (int off = 1; off < 64; off <<= 1) s2 += __shfl_xor(s2, off);
    float rstd = rsqrtf(s2 * (1.f / 256.f) + 1e-5f);
    float4 r;
    r.x = dx * rstd * g4.x + be4.x + de4.x;
    r.y = dy * rstd * g4.y + be4.y + de4.y;
    r.z = dz * rstd * g4.z + be4.z + de4.z;
    r.w = dw * rstd * g4.w + be4.w + de4.w;
    *(float4*)(&route[w][lc]) = r;
    asm volatile("s_waitcnt lgkmcnt(0)" ::: "memory");
    __builtin_amdgcn_wave_barrier();

    float a0 = 0.f, a1 = 0.f, a2 = 0.f, a3 = 0.f;
#pragma unroll
    for (int ii = 0; ii < 16; ii += 4) {
      float4 r0 = *(const float4*)(&route[w][q * 64 + (ii + 0) * 4]);
      float4 r1 = *(const float4*)(&route[w][q * 64 + (ii + 1) * 4]);
      float4 r2 = *(const float4*)(&route[w][q * 64 + (ii + 2) * 4]);
      float4 r3 = *(const float4*)(&route[w][q * 64 + (ii + 3) * 4]);
      a0 += r0.x * gwreg[ii + 0].x + r0.y * gwreg[ii + 0].y + r0.z * gwreg[ii + 0].z + r0.w * gwreg[ii + 0].w;
      a1 += r1.x * gwreg[ii + 1].x + r1.y * gwreg[ii + 1].y + r1.z * gwreg[ii + 1].z + r1.w * gwreg[ii + 1].w;
      a2 += r2.x * gwreg[ii + 2].x + r2.y * gwreg[ii + 2].y + r2.z * gwreg[ii + 2].z + r2.w * gwreg[ii + 2].w;
      a3 += r3.x * gwreg[ii + 3].x + r3.y * gwreg[ii + 3].y + r3.z * gwreg[ii + 3].z + r3.w * gwreg[ii + 3].w;
    }
    float acc = (a0 + a1) + (a2 + a3);
    acc += __shfl_xor(acc, 16);
    acc += __shfl_xor(acc, 32);
    float logit = acc + gb;

    float m = logit;
#pragma unroll
    for (int off = 1; off < 16; off <<= 1) m = fmaxf(m, __shfl_xor(m, off));
    float p = expf(logit - m);
    float sum = p;
#pragma unroll
    for (int off = 1; off < 16; off <<= 1) sum += __shfl_xor(sum, off);
    float wv = p / sum;

    float et = -wv * logf(wv + 1e-12f);
    float ent = et;
#pragma unroll
    for (int off = 1; off < 16; off <<= 1) ent += __shfl_xor(ent, off);
    float kf = ceilf(1.f + ent * (15.f / 2.7725887f));
    int k = (int)kf;
    k = max(1, min(16, k));

    int base = l & 48;
    int rank = 0;
#pragma unroll
    for (int j = 0; j < 16; j++) {
      float wj = __shfl(wv, base + j);
      rank += (wj > wv) || (wj == wv && j < e);
    }
    int sel = rank < k;
    float cmb = sel ? wv : 0.f;
    int n = n0 + i;
    if (l < 16) combine[(size_t)n * 16 + e] = cmb;
    psel += (float)sel;
    pw += wv;

    x = xn;
  }

  if (l < 16) { fred[0 * 128 + w * 16 + l] = psel; fred[1 * 128 + w * 16 + l] = pw; }
  __syncthreads();
  if (t < 32) {
    int kind = t >> 4, ee = t & 15;
    float v = 0.f;
#pragma unroll
    for (int ww = 0; ww < 8; ww++) v += fred[kind * 128 + ww * 16 + ee];
    frac_part[b * 32 + t] = v;
  }
}

// ---- kernel 2 helpers (v10) ----
// B prefetch for (expert-ptr we, quarter qn): 8 coalesced 1KB lines.
static __device__ __forceinline__ void pref_b8(
    uint4 (&breg)[8], const uint4* __restrict__ we, int qn) {
#pragma unroll
  for (int f = 0; f < 8; f++) {
    int kbl = f >> 1, d = f & 1;
    breg[f] = we[(size_t)d * 1024 + (qn * 4 + kbl) * 64];
  }
}

// one K-quarter: 8 MFMA (1 m-block x 2 d-blocks x 4 kbl), A register-resident.
static __device__ __forceinline__ void mfma8(
    f32x16 (&tacc)[2], const uint4 (&areg)[16], const uint4 (&breg)[8], int q) {
  __builtin_amdgcn_s_setprio(1);
#pragma unroll
  for (int kbl = 0; kbl < 4; kbl++) {
    short8 a  = BC8(areg[q * 4 + kbl]);
    short8 b0 = BC8(breg[kbl * 2 + 0]);
    short8 b1 = BC8(breg[kbl * 2 + 1]);
    tacc[0] = MFMA32(a, b0, tacc[0]);
    tacc[1] = MFMA32(a, b1, tacc[1]);
  }
  __builtin_amdgcn_s_setprio(0);
}

// Kernel 2 (v10): A-path eliminated from the main loop. Session A/Bs pinned
// the invariant: ~2700-3000 cyc/slot wall vs 1033 MFMA demand at ANY
// occupancy/B-path — the shared cost was 8 A ds_read/wave/slot serialized
// against MFMA (A-frag regs reused each slot). Fix: wave = 1 m-block x 2
// d-blocks (64-tok x 256-col block, grid 512), so the wave's WHOLE A set =
// 16 uint4 = 64 VGPR, loaded once from apack (coalesced, prep-packed) and
// register-resident for all 68 slots. Zero A-loads + zero LDS in main loop
// (4KB wtile only). B = v7's proven 2-buffer depth-1. Registers (v9 spill
// lesson): arch ~148 + AGPR 64 = ~212 <= 256, 40-reg margin. Block 512 =
// finalize.
__global__ __launch_bounds__(512, 2) void moe_gemm_kernel(
    const uint4* __restrict__ apack, const uint4* __restrict__ wpack,
    const float* __restrict__ combine, const float* __restrict__ expert_b,
    const float* __restrict__ share_b, float* __restrict__ out,
    const float* __restrict__ frac_part) {
  __shared__ __align__(16) float wtile[1024];   // [e][tok] 16*64 fp32 = 4 KB
  int t = threadIdx.x, b = blockIdx.x;

  if (b == 512) {   // ---- finalize branch: balance loss -> out[N*C] ----
    float* acc = wtile;   // reuse (needs 512 floats)
    int col = t & 31, seg = t >> 5;   // seg 0..15
    float s = 0.f;
    for (int i = seg; i < 512; i += 16) s += frac_part[i * 32 + col];
    acc[seg * 32 + col] = s;
    __syncthreads();
    if (t < 32) {
      float v = 0.f;
#pragma unroll
      for (int sg = 0; sg < 16; sg++) v += acc[sg * 32 + t];
      acc[t] = v;
    }
    __syncthreads();
    if (t == 0) {
      float loss = 0.f;
      for (int e = 0; e < 16; e++) {
        float ft = acc[e] * (1.f / 32768.f);
        float fp = acc[16 + e] * (1.f / 32768.f);
        loss += ft * fp;
      }
      out[8388608] = loss * 16.f;
    }
    return;
  }

  int w = t >> 6, l = t & 63;
  int mw = w >> 2;       // m-block 0..1 (rows mw*32..+31)
  int dw = w & 3;        // d-pair 0..3 (cols (dw*2+{0,1})*32)
  int r5 = l & 31, hi = l >> 5;

  // wtile transposed stage: combine[tok][e] -> wtile[e*64 + tok]
  {
    const float* cg = combine + (size_t)b * 1024;
#pragma unroll
    for (int i = 0; i < 2; i++) {
      int idx = i * 512 + t;
      wtile[(idx & 15) * 64 + (idx >> 4)] = cg[idx];
    }
  }

  // A-frags: 16 uint4 (64 VGPR), register-resident for the whole kernel.
  // apack line (kb, mb) lane l = A[mb*32+(l&31)][ch (kb*2+(l>>5))*8..+8]
  const uint4* ab = apack + (size_t)b * 2048 + mw * 64 + l;
  uint4 areg[16];
#pragma unroll
  for (int kb = 0; kb < 16; kb++) areg[kb] = ab[kb * 128];

  // B prefetch slot (e=0, q=0)
  const uint4* wb = wpack + (size_t)(dw * 2) * 1024 + l;
  uint4 bregA[8], bregB[8];
  pref_b8(bregA, wb, 0);

  __syncthreads();   // wtile visible

  f32x16 facc[2];
#pragma unroll
  for (int d = 0; d < 2; d++)
#pragma unroll
    for (int r = 0; r < 16; r++) facc[d][r] = 0.f;
  f32x16 tacc[2];
  int rowoff = hi * 4;   // C/D layout row offset

  for (int e = 0; e < 17; e++) {
    const uint4* we = wb + (size_t)e * 8192;
#pragma unroll
    for (int d = 0; d < 2; d++)
#pragma unroll
      for (int r = 0; r < 16; r++) tacc[d][r] = 0.f;

    pref_b8(bregB, we, 1);
    mfma8(tacc, areg, bregA, 0);
    pref_b8(bregA, we, 2);
    mfma8(tacc, areg, bregB, 1);
    pref_b8(bregB, we, 3);
    mfma8(tacc, areg, bregA, 2);
    if (e < 16) pref_b8(bregA, we + 8192, 0);
    mfma8(tacc, areg, bregB, 3);

    // scale-add full-K expert output: facc += w[row,e] * tacc (once per expert)
    if (e < 16) {
#pragma unroll
      for (int rg = 0; rg < 4; rg++) {
        float4 w4 = *(const float4*)&wtile[e * 64 + mw * 32 + 8 * rg + rowoff];
        float wj[4] = {w4.x, w4.y, w4.z, w4.w};
#pragma unroll
        for (int j = 0; j < 4; j++) {
          facc[0][rg * 4 + j] += wj[j] * tacc[0][rg * 4 + j];
          facc[1][rg * 4 + j] += wj[j] * tacc[1][rg * 4 + j];
        }
      }
    } else {  // shared expert, weight 1.0
#pragma unroll
      for (int r = 0; r < 16; r++) {
        facc[0][r] += tacc[0][r];
        facc[1][r] += tacc[1][r];
      }
    }
  }

  // ---- final epilogue: bias terms + store ----
  int cg0 = (dw * 2 + 0) * 32 + r5;
  int cg1 = (dw * 2 + 1) * 32 + r5;
  float sb0 = share_b[cg0], sb1 = share_b[cg1];
  float eb0[16], eb1[16];
#pragma unroll
  for (int e2 = 0; e2 < 16; e2++) {
    eb0[e2] = expert_b[e2 * 256 + cg0];
    eb1[e2] = expert_b[e2 * 256 + cg1];
  }
  // facc += sum_e w[row,e] * expert_b[e,col]
#pragma unroll
  for (int e2 = 0; e2 < 16; e2++)
#pragma unroll
    for (int rg = 0; rg < 4; rg++) {
      float4 w4 = *(const float4*)&wtile[e2 * 64 + mw * 32 + 8 * rg + rowoff];
      float wj[4] = {w4.x, w4.y, w4.z, w4.w};
#pragma unroll
      for (int j = 0; j < 4; j++) {
        facc[0][rg * 4 + j] += wj[j] * eb0[e2];
        facc[1][rg * 4 + j] += wj[j] * eb1[e2];
      }
    }
#pragma unroll
  for (int r = 0; r < 16; r++) {
    int row = mw * 32 + (r & 3) + ((r >> 2) << 3) + rowoff;
    size_t n = (size_t)b * 64 + row;
    out[n * 256 + cg0] = facc[0][r] + sb0;
    out[n * 256 + cg1] = facc[1][r] + sb1;
  }
}

extern "C" void kernel_launch(void* const* d_in, const int* in_sizes, int n_in,
                              void* d_out, int out_size, void* d_ws, size_t ws_size,
                              hipStream_t stream) {
  const float* inputs   = (const float*)d_in[0];
  const float* conv_out = (const float*)d_in[1];
  const float* demb     = (const float*)d_in[2];
  const float* share_W  = (const float*)d_in[3];
  const float* share_b  = (const float*)d_in[4];
  const float* gate_W   = (const float*)d_in[5];
  const float* gate_b   = (const float*)d_in[6];
  const float* expert_W = (const float*)d_in[7];
  const float* expert_b = (const float*)d_in[8];
  const float* ln_g     = (const float*)d_in[9];
  const float* ln_b     = (const float*)d_in[10];
  float* out = (float*)d_out;
  char* ws = (char*)d_ws;

  uint4* wpack   = (uint4*)(ws);
  uint4* apack   = (uint4*)(ws + 2228224);
  float* combine = (float*)(ws + 19005440);
  float* frac    = (float*)(ws + 21102592);

  prep_kernel<<<dim3(1296), dim3(512), 0, stream>>>(
      inputs, conv_out, demb, gate_W, gate_b, ln_g, ln_b, share_W, expert_W,
      combine, frac, wpack, apack);
  moe_gemm_kernel<<<dim3(513), dim3(512), 0, stream>>>(
      apack, wpack, combine, expert_b, share_b, out, frac);
}

// Round 13
// 227.597 us; speedup vs baseline: 1.3443x; 1.0766x over previous
//
#include <hip/hip_runtime.h>
#include <hip/hip_bf16.h>

// Problem constants
#define NTOK 32768
#define CH   256
#define NEXP 16

typedef __attribute__((ext_vector_type(8)))  short short8;   // 8 x bf16 (4 VGPR)
typedef __attribute__((ext_vector_type(16))) float f32x16;   // MFMA 32x32 accumulator

#define MFMA32(a, b, c) __builtin_amdgcn_mfma_f32_32x32x16_bf16((a), (b), (c), 0, 0, 0)
#define BC8(v) __builtin_bit_cast(short8, (v))

// async global->LDS, 16B per lane; lds ptr must be wave-uniform (dst = base + lane*16)
#define GLD16(lds, g) __builtin_amdgcn_global_load_lds(                          \
    (const __attribute__((address_space(1))) unsigned int*)(g),                  \
    (__attribute__((address_space(3))) unsigned int*)(lds), 16, 0, 0)

// fp32 -> bf16 round-to-nearest-even
static __device__ __forceinline__ unsigned short f2bf(float f) {
  unsigned int u = __builtin_bit_cast(unsigned int, f);
  unsigned int r = (u + 0x7fffu + ((u >> 16) & 1u)) >> 16;
  return (unsigned short)r;
}

// ---------------------------------------------------------------------------
// Workspace layout (bytes):
//   [0,        2228224)  W_packed  17*C*C bf16, MFMA B-fragment order
//   [2228224, 19005440)  A_packed  N*C bf16, fragment order per 64-tok tile
//   [19005440,21102592)  combine   N*16 fp32
//   [21102592,21168128)  frac_part 512*32 fp32
// ---------------------------------------------------------------------------

// Kernel 1 (R12-verified, byte-identical): FUSED prep = gate (blocks 0..511)
// + wconvert (512..783) + apack (784..1295).
__global__ __launch_bounds__(512, 2) void prep_kernel(
    const float* __restrict__ inputs, const float* __restrict__ conv_out,
    const float* __restrict__ domain_emb, const float* __restrict__ gate_W,
    const float* __restrict__ gate_b, const float* __restrict__ ln_gamma,
    const float* __restrict__ ln_beta, const float* __restrict__ share_W,
    const float* __restrict__ expert_W, float* __restrict__ combine,
    float* __restrict__ frac_part, uint4* __restrict__ wp,
    uint4* __restrict__ apack) {
  __shared__ __align__(16) char shm[33280];   // union: apack 32KB / gate ~25.9KB
  int t = threadIdx.x, b = blockIdx.x;

  if (b >= 784) {   // ---- apack branch: tile = b - 784 (64 tok) ----
    uint4* at = (uint4*)shm;   // 2048 uint4 = 32 KB, fragment order + kb-XOR
    int tile = b - 784;
#pragma unroll
    for (int i = 0; i < 4; i++) {
      int u = i * 512 + t;
      int row = u >> 5, j = u & 31;
      const float4* src = (const float4*)(inputs + ((size_t)tile * 64 + row) * 256 + j * 8);
      float4 f0 = src[0], f1 = src[1];
      unsigned int p0 = (unsigned int)f2bf(f0.x) | ((unsigned int)f2bf(f0.y) << 16);
      unsigned int p1 = (unsigned int)f2bf(f0.z) | ((unsigned int)f2bf(f0.w) << 16);
      unsigned int p2 = (unsigned int)f2bf(f1.x) | ((unsigned int)f2bf(f1.y) << 16);
      unsigned int p3 = (unsigned int)f2bf(f1.z) | ((unsigned int)f2bf(f1.w) << 16);
      int kb = j >> 1, hib = j & 1;
      at[kb * 128 + (row >> 5) * 64 + hib * 32 + ((row & 31) ^ kb)] =
          make_uint4(p0, p1, p2, p3);
    }
    __syncthreads();
#pragma unroll
    for (int i = 0; i < 4; i++) {
      int u = i * 512 + t;
      int kb = u >> 7, mb = (u >> 6) & 1, hib = (u >> 5) & 1, r5 = u & 31;
      apack[(size_t)tile * 2048 + u] = at[kb * 128 + mb * 64 + hib * 32 + (r5 ^ kb)];
    }
    return;
  }

  if (b >= 512) {   // ---- wconvert branch (R9-verified) ----
    int g = (b - 512) * 512 + t;   // 0..139263 (= 17*8192 exactly)
    int e = g >> 13;
    int r = g & 8191;
    int lane = r & 63;
    int kb = (r >> 6) & 15;
    int db = r >> 10;
    int d  = db * 32 + (lane & 31);
    int k0 = kb * 16 + ((lane >> 5) << 3);
    const float* src = (e < 16) ? (expert_W + (size_t)e * 65536) : share_W;
    unsigned int p[4];
#pragma unroll
    for (int j = 0; j < 4; j++) {
      float f0 = src[(size_t)(k0 + 2 * j) * 256 + d];
      float f1 = src[(size_t)(k0 + 2 * j + 1) * 256 + d];
      p[j] = (unsigned int)f2bf(f0) | ((unsigned int)f2bf(f1) << 16);
    }
    wp[g] = make_uint4(p[0], p[1], p[2], p[3]);
    return;
  }

  // ---- gate branch (R9-verified math; LDS carved from shm) ----
  float (*route)[256] = (float(*)[256])shm;            // 8 KB
  float* gwT = (float*)(shm + 8192);                   // 16 * 260 fp32 = 16.25 KB
  float* fred = (float*)(shm + 8192 + 16640);          // 2*8*16 fp32 = 1 KB
  int w = t >> 6, l = t & 63;

#pragma unroll
  for (int i = 0; i < 8; i++) {
    int idx = i * 512 + t;
    gwT[(idx & 15) * 260 + (idx >> 4)] = gate_W[idx];
  }
  __syncthreads();

  int lc = l * 4;
  float4 g4 = *(const float4*)(ln_gamma + lc);
  float4 be4 = *(const float4*)(ln_beta + lc);
  float4 de4 = *(const float4*)(domain_emb + lc);
  int e = l & 15, q = l >> 4;
  float gb = gate_b[e];

  float4 gwreg[16];
#pragma unroll
  for (int ii = 0; ii < 16; ii++)
    gwreg[ii] = *(const float4*)&gwT[e * 260 + q * 64 + ii * 4];

  float psel = 0.f, pw = 0.f;
  int n0 = b * 64 + w * 8;
  float4 x = *(const float4*)(conv_out + (size_t)n0 * 256 + lc);
  for (int i = 0; i < 8; i++) {
    float4 xn = *(const float4*)(conv_out + (size_t)(n0 + ((i + 1) & 7)) * 256 + lc);

    float s1 = x.x + x.y + x.z + x.w;
#pragma unroll
    for (int off = 1; off < 64; off <<= 1) s1 += __shfl_xor(s1, off);
    float mu = s1 * (1.f / 256.f);
    float dx = x.x - mu, dy = x.y - mu, dz = x.z - mu, dw = x.w - mu;
    float s2 = dx * dx + dy * dy + dz * dz + dw * dw;
#pragma unroll
    for (int off = 1; off < 64; off <<= 1) s2 += __shfl_xor(s2, off);
    float rstd = rsqrtf(s2 * (1.f / 256.f) + 1e-5f);
    float4 r;
    r.x = dx * rstd * g4.x + be4.x + de4.x;
    r.y = dy * rstd * g4.y + be4.y + de4.y;
    r.z = dz * rstd * g4.z + be4.z + de4.z;
    r.w = dw * rstd * g4.w + be4.w + de4.w;
    *(float4*)(&route[w][lc]) = r;
    asm volatile("s_waitcnt lgkmcnt(0)" ::: "memory");
    __builtin_amdgcn_wave_barrier();

    float a0 = 0.f, a1 = 0.f, a2 = 0.f, a3 = 0.f;
#pragma unroll
    for (int ii = 0; ii < 16; ii += 4) {
      float4 r0 = *(const float4*)(&route[w][q * 64 + (ii + 0) * 4]);
      float4 r1 = *(const float4*)(&route[w][q * 64 + (ii + 1) * 4]);
      float4 r2 = *(const float4*)(&route[w][q * 64 + (ii + 2) * 4]);
      float4 r3 = *(const float4*)(&route[w][q * 64 + (ii + 3) * 4]);
      a0 += r0.x * gwreg[ii + 0].x + r0.y * gwreg[ii + 0].y + r0.z * gwreg[ii + 0].z + r0.w * gwreg[ii + 0].w;
      a1 += r1.x * gwreg[ii + 1].x + r1.y * gwreg[ii + 1].y + r1.z * gwreg[ii + 1].z + r1.w * gwreg[ii + 1].w;
      a2 += r2.x * gwreg[ii + 2].x + r2.y * gwreg[ii + 2].y + r2.z * gwreg[ii + 2].z + r2.w * gwreg[ii + 2].w;
      a3 += r3.x * gwreg[ii + 3].x + r3.y * gwreg[ii + 3].y + r3.z * gwreg[ii + 3].z + r3.w * gwreg[ii + 3].w;
    }
    float acc = (a0 + a1) + (a2 + a3);
    acc += __shfl_xor(acc, 16);
    acc += __shfl_xor(acc, 32);
    float logit = acc + gb;

    float m = logit;
#pragma unroll
    for (int off = 1; off < 16; off <<= 1) m = fmaxf(m, __shfl_xor(m, off));
    float p = expf(logit - m);
    float sum = p;
#pragma unroll
    for (int off = 1; off < 16; off <<= 1) sum += __shfl_xor(sum, off);
    float wv = p / sum;

    float et = -wv * logf(wv + 1e-12f);
    float ent = et;
#pragma unroll
    for (int off = 1; off < 16; off <<= 1) ent += __shfl_xor(ent, off);
    float kf = ceilf(1.f + ent * (15.f / 2.7725887f));
    int k = (int)kf;
    k = max(1, min(16, k));

    int base = l & 48;
    int rank = 0;
#pragma unroll
    for (int j = 0; j < 16; j++) {
      float wj = __shfl(wv, base + j);
      rank += (wj > wv) || (wj == wv && j < e);
    }
    int sel = rank < k;
    float cmb = sel ? wv : 0.f;
    int n = n0 + i;
    if (l < 16) combine[(size_t)n * 16 + e] = cmb;
    psel += (float)sel;
    pw += wv;

    x = xn;
  }

  if (l < 16) { fred[0 * 128 + w * 16 + l] = psel; fred[1 * 128 + w * 16 + l] = pw; }
  __syncthreads();
  if (t < 32) {
    int kind = t >> 4, ee = t & 15;
    float v = 0.f;
#pragma unroll
    for (int ww = 0; ww < 8; ww++) v += fred[kind * 128 + ww * 16 + ee];
    frac_part[b * 32 + t] = v;
  }
}

// ---- kernel 2 helpers (v6, R5-verified) ----
static __device__ __forceinline__ void pref_b(
    uint4 (&breg)[8], const uint4* __restrict__ we, int q) {
#pragma unroll
  for (int f = 0; f < 8; f++) {
    int kbl = f >> 1, d = f & 1;
    breg[f] = we[(size_t)d * 1024 + (q * 4 + kbl) * 64];
  }
}

static __device__ __forceinline__ void slot_mfma(
    f32x16 (&tacc)[2][2], const f32x16& zc, const uint4* __restrict__ at,
    const uint4 (&breg)[8], int q, int abase_kb_stride_l, int mbp, int l,
    bool first) {
  (void)abase_kb_stride_l;
  __builtin_amdgcn_s_setprio(1);
#pragma unroll
  for (int kbl = 0; kbl < 4; kbl++) {
    int g0 = ((q * 4 + kbl) * 4 + (mbp * 2 + 0)) * 64 + l;
    int g1 = ((q * 4 + kbl) * 4 + (mbp * 2 + 1)) * 64 + l;
    short8 a0 = BC8(at[g0]);
    short8 a1 = BC8(at[g1]);
    short8 b0 = BC8(breg[kbl * 2 + 0]);
    short8 b1 = BC8(breg[kbl * 2 + 1]);
    if (first && kbl == 0) {
      tacc[0][0] = MFMA32(a0, b0, zc);
      tacc[0][1] = MFMA32(a0, b1, zc);
      tacc[1][0] = MFMA32(a1, b0, zc);
      tacc[1][1] = MFMA32(a1, b1, zc);
    } else {
      tacc[0][0] = MFMA32(a0, b0, tacc[0][0]);
      tacc[0][1] = MFMA32(a0, b1, tacc[0][1]);
      tacc[1][0] = MFMA32(a1, b0, tacc[1][0]);
      tacc[1][1] = MFMA32(a1, b1, tacc[1][1]);
    }
  }
  __builtin_amdgcn_s_setprio(0);
}

// Kernel 2 (R13 = R5's v6 gemm VERBATIM + R12's finalize branch at b==256):
// the session's measured-best GEMM (75.5 us, MfmaUtil 45.5). 128-tok tiles,
// A via GLD16 from apack (R12 prep layout = R5 layout, re-derived identical),
// B global->VGPR depth-1 double-buffer, barrier-free e-outer/q-inner loop,
// scale-add once per expert. v8/v9/v10 A/Bs showed all (mb,db) wave shapes
// and occupancy variants have equal-or-worse pipe-demand sums — v6 is the
// local optimum of this family; consolidating before the next structural
// experiment.
__global__ __launch_bounds__(512, 2) void moe_gemm_kernel(
    const uint4* __restrict__ apack, const uint4* __restrict__ wpack,
    const float* __restrict__ combine, const float* __restrict__ expert_b,
    const float* __restrict__ share_b, float* __restrict__ out,
    const float* __restrict__ frac_part) {
  extern __shared__ __align__(16) char smem[];
  int t = threadIdx.x, b = blockIdx.x;

  if (b == 256) {   // ---- finalize branch: balance loss -> out[N*C] ----
    float* acc = (float*)smem;   // [16][32]
    int col = t & 31, seg = t >> 5;
    float s = 0.f;
    for (int i = seg; i < 512; i += 16) s += frac_part[i * 32 + col];
    acc[seg * 32 + col] = s;
    __syncthreads();
    if (t < 32) {
      float v = 0.f;
#pragma unroll
      for (int sg = 0; sg < 16; sg++) v += acc[sg * 32 + t];
      acc[t] = v;
    }
    __syncthreads();
    if (t == 0) {
      float loss = 0.f;
      for (int e = 0; e < 16; e++) {
        float ft = acc[e] * (1.f / 32768.f);
        float fp = acc[16 + e] * (1.f / 32768.f);
        loss += ft * fp;
      }
      out[8388608] = loss * 16.f;
    }
    return;
  }

  uint4* atile = (uint4*)smem;              // 4096 uint4 = 64 KB
  float* wtile = (float*)(smem + 65536);    // [e][row] 16*128 fp32 = 8 KB

  int w = t >> 6, l = t & 63;
  int mbp = w >> 2;      // 0..1 -> rows (mbp*2+{0,1})*32
  int dbp = w & 3;       // 0..3 -> cols (dbp*2+{0,1})*32

  // ---- initial stages ----
  // A: 64 line-groups (kb 0..15 x mb 0..3), 8 per wave, from two 64-tok tiles
#pragma unroll
  for (int i = 0; i < 8; i++) {
    int g = w * 8 + i;
    int kb = g >> 2, mb = g & 3;
    const uint4* src = apack + ((size_t)(2 * b + (mb >> 1)) * 2048 + (size_t)(kb * 2 + (mb & 1)) * 64 + l);
    GLD16(atile + g * 64, src);
  }
  // wtile transposed stage: combine[tok][e] -> wtile[e*128 + tok]
  {
    const float* cg = combine + (size_t)b * 2048;
#pragma unroll
    for (int i = 0; i < 4; i++) {
      int idx = i * 512 + t;
      wtile[(idx & 15) * 128 + (idx >> 4)] = cg[idx];
    }
  }

  // early B prefetch for (e=0, q=0)
  const uint4* wb = wpack + (size_t)(dbp * 2) * 1024 + l;
  uint4 bregA[8], bregB[8];
  pref_b(bregA, wb, 0);

  __syncthreads();   // drains GLD16 (vmcnt) + wtile ds_writes (lgkmcnt)

  f32x16 facc[2][2];
#pragma unroll
  for (int mi = 0; mi < 2; mi++)
#pragma unroll
    for (int d = 0; d < 2; d++)
#pragma unroll
      for (int r = 0; r < 16; r++) facc[mi][d][r] = 0.f;
  f32x16 zc;
#pragma unroll
  for (int r = 0; r < 16; r++) zc[r] = 0.f;

  f32x16 tacc[2][2];
  int rowoff = (l >> 5) * 4;   // C/D layout row offset for this half-wave

  for (int e = 0; e < 17; e++) {
    const uint4* we = wb + (size_t)e * 8192;
    pref_b(bregB, we, 1);
    slot_mfma(tacc, zc, atile, bregA, 0, 0, mbp, l, true);
    pref_b(bregA, we, 2);
    slot_mfma(tacc, zc, atile, bregB, 1, 0, mbp, l, false);
    pref_b(bregB, we, 3);
    slot_mfma(tacc, zc, atile, bregA, 2, 0, mbp, l, false);
    if (e < 16) pref_b(bregA, we + 8192, 0);
    slot_mfma(tacc, zc, atile, bregB, 3, 0, mbp, l, false);

    // scale-add full-K expert output: facc += w[row,e] * tacc (once per expert)
    if (e < 16) {
#pragma unroll
      for (int mi = 0; mi < 2; mi++)
#pragma unroll
        for (int rg = 0; rg < 4; rg++) {
          float4 w4 = *(const float4*)&wtile[e * 128 + (mbp * 2 + mi) * 32 + 8 * rg + rowoff];
          float wj[4] = {w4.x, w4.y, w4.z, w4.w};
#pragma unroll
          for (int j = 0; j < 4; j++) {
            facc[mi][0][rg * 4 + j] += wj[j] * tacc[mi][0][rg * 4 + j];
            facc[mi][1][rg * 4 + j] += wj[j] * tacc[mi][1][rg * 4 + j];
          }
        }
    } else {  // shared expert, weight 1.0
#pragma unroll
      for (int mi = 0; mi < 2; mi++)
#pragma unroll
        for (int r = 0; r < 16; r++) {
          facc[mi][0][r] += tacc[mi][0][r];
          facc[mi][1][r] += tacc[mi][1][r];
        }
    }
  }

  // ---- final epilogue: bias terms + store ----
  int col = l & 31;
  int cg0 = (dbp * 2 + 0) * 32 + col;
  int cg1 = (dbp * 2 + 1) * 32 + col;
  float sb0 = share_b[cg0], sb1 = share_b[cg1];
  float eb0[16], eb1[16];
#pragma unroll
  for (int e2 = 0; e2 < 16; e2++) {
    eb0[e2] = expert_b[e2 * 256 + cg0];
    eb1[e2] = expert_b[e2 * 256 + cg1];
  }
  // facc += sum_e w[row,e] * expert_b[e,col]
#pragma unroll
  for (int e2 = 0; e2 < 16; e2++)
#pragma unroll
    for (int mi = 0; mi < 2; mi++)
#pragma unroll
      for (int rg = 0; rg < 4; rg++) {
        float4 w4 = *(const float4*)&wtile[e2 * 128 + (mbp * 2 + mi) * 32 + 8 * rg + rowoff];
        float wj[4] = {w4.x, w4.y, w4.z, w4.w};
#pragma unroll
        for (int j = 0; j < 4; j++) {
          facc[mi][0][rg * 4 + j] += wj[j] * eb0[e2];
          facc[mi][1][rg * 4 + j] += wj[j] * eb1[e2];
        }
      }
#pragma unroll
  for (int mi = 0; mi < 2; mi++)
#pragma unroll
    for (int r = 0; r < 16; r++) {
      int row = (mbp * 2 + mi) * 32 + (r & 3) + ((r >> 2) << 3) + rowoff;
      size_t n = (size_t)b * 128 + row;
      out[n * 256 + cg0] = facc[mi][0][r] + sb0;
      out[n * 256 + cg1] = facc[mi][1][r] + sb1;
    }
}

extern "C" void kernel_launch(void* const* d_in, const int* in_sizes, int n_in,
                              void* d_out, int out_size, void* d_ws, size_t ws_size,
                              hipStream_t stream) {
  const float* inputs   = (const float*)d_in[0];
  const float* conv_out = (const float*)d_in[1];
  const float* demb     = (const float*)d_in[2];
  const float* share_W  = (const float*)d_in[3];
  const float* share_b  = (const float*)d_in[4];
  const float* gate_W   = (const float*)d_in[5];
  const float* gate_b   = (const float*)d_in[6];
  const float* expert_W = (const float*)d_in[7];
  const float* expert_b = (const float*)d_in[8];
  const float* ln_g     = (const float*)d_in[9];
  const float* ln_b     = (const float*)d_in[10];
  float* out = (float*)d_out;
  char* ws = (char*)d_ws;

  uint4* wpack   = (uint4*)(ws);
  uint4* apack   = (uint4*)(ws + 2228224);
  float* combine = (float*)(ws + 19005440);
  float* frac    = (float*)(ws + 21102592);

  // allow 72 KB dynamic LDS (idempotent; not a stream op, safe under capture)
  hipFuncSetAttribute((const void*)moe_gemm_kernel,
                      hipFuncAttributeMaxDynamicSharedMemorySize, 73728);

  prep_kernel<<<dim3(1296), dim3(512), 0, stream>>>(
      inputs, conv_out, demb, gate_W, gate_b, ln_g, ln_b, share_W, expert_W,
      combine, frac, wpack, apack);
  moe_gemm_kernel<<<dim3(257), dim3(512), 73728, stream>>>(
      apack, wpack, combine, expert_b, share_b, out, frac);
}